// Round 17
// baseline (724.375 us; speedup 1.0000x reference)
//
#include <hip/hip_runtime.h>
#include <hip/hip_bf16.h>

typedef __attribute__((ext_vector_type(4))) float f32x4;
typedef __attribute__((ext_vector_type(8))) short s16x8;
typedef __attribute__((ext_vector_type(4))) unsigned short u16x4;
typedef __attribute__((ext_vector_type(8))) unsigned short u16x8;
typedef __attribute__((ext_vector_type(4))) int i32x4;

#define NB 64
#define NS 256
#define ND 2048
#define NH 16
#define NHD 128

__device__ __forceinline__ unsigned short f2bf(float f){
  unsigned int u = __float_as_uint(f);
  u += 0x7fffu + ((u >> 16) & 1u);
  return (unsigned short)(u >> 16);
}

__device__ __forceinline__ void gload16(const void* g, void* l){
  __builtin_amdgcn_global_load_lds(
    (const __attribute__((address_space(1))) unsigned int*)g,
    (__attribute__((address_space(3))) unsigned int*)l, 16, 0, 0);
}

#define SBAR()  __builtin_amdgcn_sched_barrier(0)
#define BARRIER() do{ SBAR(); __builtin_amdgcn_s_barrier(); SBAR(); }while(0)
#define WAIT_LGKM0() do{ asm volatile("s_waitcnt lgkmcnt(0)" ::: "memory"); SBAR(); }while(0)
#define WAIT_VM0()   do{ asm volatile("s_waitcnt vmcnt(0)"   ::: "memory"); SBAR(); }while(0)
#define WAIT_VM8()   do{ asm volatile("s_waitcnt vmcnt(8)"   ::: "memory"); SBAR(); }while(0)

// ---------------- fp32 -> bf16 conversion ----------------
__global__ __launch_bounds__(256) void wconv(const float* __restrict__ s,
                                             unsigned short* __restrict__ d, int n8){
  int i = blockIdx.x*256 + threadIdx.x;
  if (i >= n8) return;
  f32x4 a = *(const f32x4*)(s + (size_t)i*8);
  f32x4 b = *(const f32x4*)(s + (size_t)i*8 + 4);
  u16x8 u;
  #pragma unroll
  for (int r=0;r<4;r++){ u[r]=f2bf(a[r]); u[4+r]=f2bf(b[r]); }
  *(u16x8*)(d + (size_t)i*8) = u;
}

// all four weight matrices in one dispatch (grid 8192, 2048 blocks each)
__global__ __launch_bounds__(256) void wconv4(
  const float* __restrict__ s0, const float* __restrict__ s1,
  const float* __restrict__ s2, const float* __restrict__ s3,
  unsigned short* __restrict__ d0, unsigned short* __restrict__ d1,
  unsigned short* __restrict__ d2, unsigned short* __restrict__ d3)
{
  int j = blockIdx.x >> 11;
  const float* s = (j==0)?s0:(j==1)?s1:(j==2)?s2:s3;
  unsigned short* d = (j==0)?d0:(j==1)?d1:(j==2)?d2:d3;
  int i = (blockIdx.x & 2047)*256 + threadIdx.x;
  f32x4 a = *(const f32x4*)(s + (size_t)i*8);
  f32x4 b = *(const f32x4*)(s + (size_t)i*8 + 4);
  u16x8 u;
  #pragma unroll
  for (int r=0;r<4;r++){ u[r]=f2bf(a[r]); u[4+r]=f2bf(b[r]); }
  *(u16x8*)(d + (size_t)i*8) = u;
}

// ================= shared GEMM fragment macros =================
// XCD map: round-14 proven. swz = (bid&7)*(nwg>>3) + (bid>>3): each XCD owns
// a contiguous mt-band (A read ONCE chip-wide, 98 MB FETCH).
#define GEMM_COMMON_DECLS \
  extern __shared__ __attribute__((aligned(16))) char ldsb[]; \
  const int tid  = threadIdx.x; \
  const int lane = tid & 63, wid = tid >> 6; \
  const int g = lane >> 4, l15 = lane & 15; \
  const int wm = wid >> 2, wn = wid & 3; \
  const int nwg = gridDim.x, bid = blockIdx.x; \
  const int swz = (bid & 7) * (nwg >> 3) + (bid >> 3); \
  const int mt = swz >> 3, nt = swz & 7; \
  const int m0 = mt*256, n0 = nt*256; \
  const int srow_l = tid >> 3, slot = tid & 7;

#define RD_A(buf, qa) do{ \
    _Pragma("unroll") for (int i_=0;i_<4;i_++){ \
      int hr = (qa)*64 + i_*16 + l15; \
      const char* p_ = ldsb + (buf)*65536 + wm*16384 + hr*128; \
      _Pragma("unroll") for (int ks_=0;ks_<2;ks_++) \
        av[i_][ks_] = *(const s16x8*)(p_ + (((ks_*4+g) ^ (hr&7))*16)); } }while(0)

#define RD_B(buf, dst, qb) do{ \
    _Pragma("unroll") for (int j_=0;j_<2;j_++){ \
      int hc = (wn&1)*64 + (qb)*32 + j_*16 + l15; \
      const char* p_ = ldsb + (buf)*65536 + 32768 + (wn>>1)*16384 + hc*128; \
      _Pragma("unroll") for (int ks_=0;ks_<2;ks_++) \
        dst[j_][ks_] = *(const s16x8*)(p_ + (((ks_*4+g) ^ (hc&7))*16)); } }while(0)

// Operand order selected by constexpr SWAPOP (declared in kernel):
// SWAPOP=0: C-frag row(g*4+r)=m, col(l15)=n (needed for OUTMODE 1, contiguous s)
// SWAPOP=1: C-frag row(g*4+r)=n, col(l15)=m (OUTMODE 0/2: lane holds 4
//           consecutive n -> vectorized u16x4 / f32x4 stores along d / n)
#define MFMA_PH(qa, qb, bv) do{ \
    __builtin_amdgcn_s_setprio(1); \
    _Pragma("unroll") for (int i_=0;i_<4;i_++) \
      _Pragma("unroll") for (int j_=0;j_<2;j_++) \
        _Pragma("unroll") for (int ks_=0;ks_<2;ks_++){ \
          if constexpr (SWAPOP) \
            acc[(qa)*4+i_][(qb)*2+j_] = __builtin_amdgcn_mfma_f32_16x16x32_bf16( \
                bv[j_][ks_], av[i_][ks_], acc[(qa)*4+i_][(qb)*2+j_], 0,0,0); \
          else \
            acc[(qa)*4+i_][(qb)*2+j_] = __builtin_amdgcn_mfma_f32_16x16x32_bf16( \
                av[i_][ks_], bv[j_][ks_], acc[(qa)*4+i_][(qb)*2+j_], 0,0,0); \
        } \
    __builtin_amdgcn_s_setprio(0); }while(0)

// ---------------- gemm256: fine+deep schedule, round-14 XCD map ----------------
// OUTMODE 0: bf16 [b][h][s][hd] (swapped, u16x4 along d)
// OUTMODE 1: bf16 V^T [b][h][d][s] (unswapped, u16x4 along s)
// OUTMODE 2: fp32 [m][n] (swapped, f32x4 along n)
template<int OUTMODE>
__global__ __launch_bounds__(512, 2) void gemm256(
    const unsigned short* __restrict__ A, const unsigned short* __restrict__ Bw,
    const float* __restrict__ bias, void* __restrict__ Out)
{
  GEMM_COMMON_DECLS
  constexpr bool SWAPOP = (OUTMODE != 1);
  const int scol = ((slot ^ (srow_l & 7)) * 8);
  const unsigned short* gsrc[4];
  gsrc[0] = A  + (size_t)(m0 +       srow_l)*ND + scol;
  gsrc[1] = A  + (size_t)(m0 + 128 + srow_l)*ND + scol;
  gsrc[2] = Bw + (size_t)(n0 +       srow_l)*ND + scol;
  gsrc[3] = Bw + (size_t)(n0 + 128 + srow_l)*ND + scol;

#define STAGE(buf, p, kt) do{ \
    const unsigned short* s_ = gsrc[p] + (kt); \
    char* d_ = ldsb + (buf)*65536 + ((p)>>1)*32768 + ((p)&1)*16384 + tid*16; \
    gload16(s_, d_); gload16(s_ + (size_t)64*ND, d_ + 8192); }while(0)

// wmode: 0 = steady WAIT_VM8 ; 1 = WAIT_VM0 (tile 30) ; -1 = none (tile 31)
#define HALF(d, ktN, wmode) do{ \
    RD_A(d,0); RD_B(d,bva,0); \
    WAIT_LGKM0(); \
    MFMA_PH(0,0,bva); \
    BARRIER(); \
    RD_B(d,bvb,1); \
    WAIT_LGKM0(); \
    MFMA_PH(0,1,bvb); \
    BARRIER(); \
    RD_A(d,1); \
    if ((ktN)>=0){ STAGE(d,2,ktN); STAGE(d,3,ktN); } \
    WAIT_LGKM0(); \
    MFMA_PH(1,0,bva); \
    BARRIER(); \
    if ((ktN)>=0){ STAGE(d,0,ktN); STAGE(d,1,ktN); } \
    MFMA_PH(1,1,bvb); \
    if ((wmode)==0){ WAIT_VM8(); } \
    else if ((wmode)==1){ WAIT_VM0(); } \
    BARRIER(); \
  }while(0)

  f32x4 acc[8][4];
  s16x8 av[4][2], bva[2][2], bvb[2][2];

  // prologue: tile 0 -> dbuf0 (8 loads), tile 1 -> dbuf1 (8 loads)
  STAGE(0,0,0); STAGE(0,1,0); STAGE(0,2,0); STAGE(0,3,0);
  STAGE(1,0,64); STAGE(1,1,64); STAGE(1,2,64); STAGE(1,3,64);
  #pragma unroll
  for (int i=0;i<8;i++)
    #pragma unroll
    for (int j=0;j<4;j++) acc[i][j] = f32x4{0.f,0.f,0.f,0.f};
  WAIT_VM8();    // tile 0 landed; tile 1 in flight
  BARRIER();

  for (int t = 0; t < 15; ++t) {
    HALF(0, (2*t+2)*64, 0);   // tile 2t   ; stage tile 2t+2 -> dbuf0
    HALF(1, (2*t+3)*64, 0);   // tile 2t+1 ; stage tile 2t+3 -> dbuf1
  }
  HALF(0, -1, 1);             // tile 30 ; drain (tile 31 lands)
  HALF(1, -1, -1);            // tile 31

  // ---------------- epilogue ----------------
  if constexpr (OUTMODE == 1) {
    // unswapped: col(l15)=n, row(g*4+r)=m -> u16x4 contiguous along s
    #pragma unroll
    for (int jx=0;jx<4;jx++){
      int n = n0 + wn*64 + ((jx>>1)<<5) + ((jx&1)<<4) + l15;
      float bj = bias[n];
      #pragma unroll
      for (int i=0;i<8;i++){
        int mb = m0 + wm*128 + ((i>>2)<<6) + ((i&3)<<4) + g*4;
        unsigned short* O = (unsigned short*)Out;
        int bb = mb >> 8, h = n >> 7, d = n & 127, s0 = mb & 255;
        u16x4 u;
        #pragma unroll
        for (int r=0;r<4;r++) u[r] = f2bf(acc[i][jx][r] + bj);
        *(u16x4*)(O + (((size_t)bb*NH + h)*NHD + d)*NS + s0) = u;
      }
    }
  } else {
    // swapped: row(g*4+r)=n, col(l15)=m -> lane holds 4 consecutive n
    #pragma unroll
    for (int jx=0;jx<4;jx++){
      int nb = n0 + wn*64 + ((jx>>1)<<5) + ((jx&1)<<4) + g*4;
      f32x4 b4 = *(const f32x4*)(bias + nb);
      #pragma unroll
      for (int i=0;i<8;i++){
        int m = m0 + wm*128 + ((i>>2)<<6) + ((i&3)<<4) + l15;
        if constexpr (OUTMODE == 2){
          float* O = (float*)Out;
          f32x4 o;
          #pragma unroll
          for (int r=0;r<4;r++) o[r] = acc[i][jx][r] + b4[r];
          *(f32x4*)(O + (size_t)m*ND + nb) = o;
        } else {
          unsigned short* O = (unsigned short*)Out;
          int bb = m >> 8, s0 = m & 255, h = nb >> 7, d = nb & 127;
          u16x4 u;
          #pragma unroll
          for (int r=0;r<4;r++) u[r] = f2bf(acc[i][jx][r] + b4[r]);
          *(u16x4*)(O + (((size_t)bb*NH + h)*NS + s0)*NHD + d) = u;
        }
      }
    }
  }
#undef STAGE
#undef HALF
}

// ---------------- fused attention v6 (unchanged from round 16) ----------------
__global__ __launch_bounds__(256, 2) void attn_fused6(
  const unsigned short* __restrict__ Qh, const unsigned short* __restrict__ Kh,
  const unsigned short* __restrict__ VT, const int* __restrict__ mask,
  const float* __restrict__ bias_table, unsigned short* __restrict__ AO)
{
  __shared__ unsigned short KV[256*128];   // 64 KB: K tile, then V^T tile
  char* KVb = (char*)KV;
  const int bid = blockIdx.x;
  const int bh = (((bid >> 3) >> 2) << 3) | (bid & 7);
  const int qt = (bid >> 3) & 3;
  const int b = bh >> 4, h = bh & 15;
  const int tid = threadIdx.x, lane = tid & 63, w = tid >> 6;
  const int g = lane >> 4, l15 = lane & 15;
  const int q = qt*64 + w*16 + l15;

  {
    const unsigned short* Ksrc = Kh + (size_t)bh*NS*NHD;
    int r0 = tid >> 4, sl = tid & 15;
    #pragma unroll
    for (int c=0;c<16;c++){
      int row = c*16 + r0;
      gload16(Ksrc + (size_t)row*NHD + ((sl ^ (row&7))*8), KVb + c*4096 + tid*16);
    }
  }
  const unsigned short* Qrow = Qh + ((size_t)bh*NS + q)*NHD;
  s16x8 bq[4];
  #pragma unroll
  for (int kk=0;kk<4;kk++) bq[kk] = *(const s16x8*)(Qrow + kk*32 + g*8);
  const float* brow = bias_table + ((size_t)h*NS + q)*NS;
  const int*   mrow = mask + b*NS;
  f32x4 br[16];
  i32x4 mr[16];
  #pragma unroll
  for (int kb=0;kb<16;kb++){
    br[kb] = *(const f32x4*)(brow + kb*16 + g*4);
    mr[kb] = *(const i32x4*)(mrow + kb*16 + g*4);
  }

  WAIT_VM0();
  BARRIER();   // K valid

  f32x4 c[16];
  __builtin_amdgcn_s_setprio(1);
  #pragma unroll
  for (int kb=0;kb<16;kb++){
    c[kb] = f32x4{0.f,0.f,0.f,0.f};
    int row = kb*16 + l15;
    #pragma unroll
    for (int kk=0;kk<4;kk++){
      s16x8 a = *(const s16x8*)(KVb + row*256 + (((kk*4+g) ^ (row&7))*16));
      c[kb] = __builtin_amdgcn_mfma_f32_16x16x32_bf16(a, bq[kk], c[kb], 0,0,0);
    }
  }
  __builtin_amdgcn_s_setprio(0);

  WAIT_LGKM0();
  BARRIER();      // K dead -> safe to overwrite

  {
    const unsigned short* Vsrc = VT + (size_t)bh*NHD*NS;
    int r0 = tid >> 5, sl = tid & 31;
    #pragma unroll
    for (int c2=0;c2<16;c2++){
      int row = c2*8 + r0;
      gload16(Vsrc + (size_t)row*NS + ((sl ^ (row&7))*8), KVb + c2*4096 + tid*16);
    }
  }

  const float scale = 0.08838834764831845f;
  float mx = -3.0e38f;
  #pragma unroll
  for (int kb=0;kb<16;kb++){
    #pragma unroll
    for (int r=0;r<4;r++){
      float val = (mr[kb][r] != 0) ? (c[kb][r]*scale + br[kb][r]) : -3.0e38f;
      c[kb][r] = val;
      mx = fmaxf(mx, val);
    }
  }
  mx = fmaxf(mx, __shfl_xor(mx, 16));
  mx = fmaxf(mx, __shfl_xor(mx, 32));
  float sum = 0.f;
  #pragma unroll
  for (int kb=0;kb<16;kb++)
    #pragma unroll
    for (int r=0;r<4;r++){
      float pv = __expf(c[kb][r] - mx);
      c[kb][r] = pv; sum += pv;
    }
  sum += __shfl_xor(sum, 16);
  sum += __shfl_xor(sum, 32);
  float inv = 1.f / sum;

  unsigned int pk[16][2];
  #pragma unroll
  for (int kb=0;kb<16;kb++){
    pk[kb][0] = (unsigned int)f2bf(c[kb][0]*inv) | ((unsigned int)f2bf(c[kb][1]*inv) << 16);
    pk[kb][1] = (unsigned int)f2bf(c[kb][2]*inv) | ((unsigned int)f2bf(c[kb][3]*inv) << 16);
  }

  WAIT_VM0();   // V landed
  BARRIER();

  const int s0l = l15 + ((g&1)<<5), s1l = s0l + 16;
  const int sel = g >> 1;
  s16x8 pb[8];
  #pragma unroll
  for (int kk=0;kk<8;kk++){
    unsigned int e0 = (unsigned int)__shfl((int)pk[2*kk][0],   s0l);
    unsigned int e1 = (unsigned int)__shfl((int)pk[2*kk][1],   s0l);
    unsigned int e2 = (unsigned int)__shfl((int)pk[2*kk][0],   s1l);
    unsigned int e3 = (unsigned int)__shfl((int)pk[2*kk][1],   s1l);
    unsigned int o0 = (unsigned int)__shfl((int)pk[2*kk+1][0], s0l);
    unsigned int o1 = (unsigned int)__shfl((int)pk[2*kk+1][1], s0l);
    unsigned int o2 = (unsigned int)__shfl((int)pk[2*kk+1][0], s1l);
    unsigned int o3 = (unsigned int)__shfl((int)pk[2*kk+1][1], s1l);
    union { unsigned int wd[4]; s16x8 v; } u_;
    u_.wd[0] = sel ? o0 : e0; u_.wd[1] = sel ? o1 : e1;
    u_.wd[2] = sel ? o2 : e2; u_.wd[3] = sel ? o3 : e3;
    pb[kk] = u_.v;
  }

  f32x4 oacc[8];
  __builtin_amdgcn_s_setprio(1);
  #pragma unroll
  for (int dt=0;dt<8;dt++){
    oacc[dt] = f32x4{0.f,0.f,0.f,0.f};
    int row = dt*16 + l15;
    #pragma unroll
    for (int kk=0;kk<8;kk++){
      s16x8 a = *(const s16x8*)(KVb + row*512 + (((kk*4+g) ^ (row&7))*16));
      oacc[dt] = __builtin_amdgcn_mfma_f32_16x16x32_bf16(a, pb[kk], oacc[dt], 0,0,0);
    }
  }
  __builtin_amdgcn_s_setprio(0);

  #pragma unroll
  for (int dt=0;dt<8;dt++){
    u16x4 u;
    #pragma unroll
    for (int r=0;r<4;r++) u[r] = f2bf(oacc[dt][r]);
    *(u16x4*)(AO + ((size_t)b*NS + q)*ND + h*NHD + dt*16 + g*4) = u;
  }
}

extern "C" void kernel_launch(void* const* d_in, const int* in_sizes, int n_in,
                              void* d_out, int out_size, void* d_ws, size_t ws_size,
                              hipStream_t stream)
{
  const float* q  = (const float*)d_in[0];
  const float* k  = (const float*)d_in[1];
  const float* v  = (const float*)d_in[2];
  const int* mask = (const int*)d_in[3];
  const float* Wq = (const float*)d_in[4];
  const float* bq = (const float*)d_in[5];
  const float* Wk = (const float*)d_in[6];
  const float* bk = (const float*)d_in[7];
  const float* Wv = (const float*)d_in[8];
  const float* bv = (const float*)d_in[9];
  const float* Wo = (const float*)d_in[10];
  const float* bo = (const float*)d_in[11];
  const float* bias_table = (const float*)d_in[12];

  // workspace layout, max 352 MiB (proven in rounds 1/3):
  //   Wqb [0,8M) Wkb [8M,16M) Wvb [16M,24M) Wob [24M,32M)
  //   tmp [32M,96M) (full-M bf16 activations, reused q->k->v)
  //   Qh [96M,160M)  Kh [160M,224M)  VT [224M,288M)  AO [288M,352M)
  char* ws = (char*)d_ws;
  unsigned short* Wqb = (unsigned short*)(ws + 0);
  unsigned short* Wkb = (unsigned short*)(ws + 8388608);
  unsigned short* Wvb = (unsigned short*)(ws + 16777216);
  unsigned short* Wob = (unsigned short*)(ws + 25165824);
  unsigned short* tmp = (unsigned short*)(ws + 33554432);
  unsigned short* Qh  = (unsigned short*)(ws + 100663296);
  unsigned short* Kh  = (unsigned short*)(ws + 167772160);
  unsigned short* VT  = (unsigned short*)(ws + 234881024);
  unsigned short* AO  = (unsigned short*)(ws + 301989888);

  hipFuncSetAttribute((const void*)gemm256<0>, hipFuncAttributeMaxDynamicSharedMemorySize, 131072);
  hipFuncSetAttribute((const void*)gemm256<1>, hipFuncAttributeMaxDynamicSharedMemorySize, 131072);
  hipFuncSetAttribute((const void*)gemm256<2>, hipFuncAttributeMaxDynamicSharedMemorySize, 131072);

  wconv4<<<8192,256,0,stream>>>(Wq,Wk,Wv,Wo, Wqb,Wkb,Wvb,Wob);

  const float* acts[3] = {q, k, v};
  const unsigned short* wgt[3] = {Wqb, Wkb, Wvb};
  const float* bia[3] = {bq, bk, bv};
  unsigned short* outs[3] = {Qh, Kh, VT};

  for (int x = 0; x < 3; ++x) {
    wconv<<<16384,256,0,stream>>>(acts[x], tmp, 4194304);
    if (x < 2)
      gemm256<0><<<512,512,131072,stream>>>(tmp, wgt[x], bia[x], outs[x]);
    else
      gemm256<1><<<512,512,131072,stream>>>(tmp, wgt[x], bia[x], outs[x]);
  }

  attn_fused6<<<4096,256,0,stream>>>(Qh,Kh,VT,mask,bias_table,AO);
  gemm256<2><<<512,512,131072,stream>>>(AO,Wob,bo,(float*)d_out);
}

// Round 18
// 702.551 us; speedup vs baseline: 1.0311x; 1.0311x over previous
//
#include <hip/hip_runtime.h>
#include <hip/hip_bf16.h>

typedef __attribute__((ext_vector_type(4))) float f32x4;
typedef __attribute__((ext_vector_type(8))) short s16x8;
typedef __attribute__((ext_vector_type(4))) unsigned short u16x4;
typedef __attribute__((ext_vector_type(8))) unsigned short u16x8;
typedef __attribute__((ext_vector_type(4))) int i32x4;

#define NB 64
#define NS 256
#define ND 2048
#define NH 16
#define NHD 128

__device__ __forceinline__ unsigned short f2bf(float f){
  unsigned int u = __float_as_uint(f);
  u += 0x7fffu + ((u >> 16) & 1u);
  return (unsigned short)(u >> 16);
}

__device__ __forceinline__ void gload16(const void* g, void* l){
  __builtin_amdgcn_global_load_lds(
    (const __attribute__((address_space(1))) unsigned int*)g,
    (__attribute__((address_space(3))) unsigned int*)l, 16, 0, 0);
}

#define SBAR()  __builtin_amdgcn_sched_barrier(0)
#define BARRIER() do{ SBAR(); __builtin_amdgcn_s_barrier(); SBAR(); }while(0)
#define WAIT_LGKM0() do{ asm volatile("s_waitcnt lgkmcnt(0)" ::: "memory"); SBAR(); }while(0)
#define WAIT_VM0()   do{ asm volatile("s_waitcnt vmcnt(0)"   ::: "memory"); SBAR(); }while(0)
#define WAIT_VM8()   do{ asm volatile("s_waitcnt vmcnt(8)"   ::: "memory"); SBAR(); }while(0)

// ---------------- fp32 -> bf16 conversion ----------------
__global__ __launch_bounds__(256) void wconv(const float* __restrict__ s,
                                             unsigned short* __restrict__ d, int n8){
  int i = blockIdx.x*256 + threadIdx.x;
  if (i >= n8) return;
  f32x4 a = *(const f32x4*)(s + (size_t)i*8);
  f32x4 b = *(const f32x4*)(s + (size_t)i*8 + 4);
  u16x8 u;
  #pragma unroll
  for (int r=0;r<4;r++){ u[r]=f2bf(a[r]); u[4+r]=f2bf(b[r]); }
  *(u16x8*)(d + (size_t)i*8) = u;
}

// all four weight matrices in one dispatch (grid 8192, 2048 blocks each)
__global__ __launch_bounds__(256) void wconv4(
  const float* __restrict__ s0, const float* __restrict__ s1,
  const float* __restrict__ s2, const float* __restrict__ s3,
  unsigned short* __restrict__ d0, unsigned short* __restrict__ d1,
  unsigned short* __restrict__ d2, unsigned short* __restrict__ d3)
{
  int j = blockIdx.x >> 11;
  const float* s = (j==0)?s0:(j==1)?s1:(j==2)?s2:s3;
  unsigned short* d = (j==0)?d0:(j==1)?d1:(j==2)?d2:d3;
  int i = (blockIdx.x & 2047)*256 + threadIdx.x;
  f32x4 a = *(const f32x4*)(s + (size_t)i*8);
  f32x4 b = *(const f32x4*)(s + (size_t)i*8 + 4);
  u16x8 u;
  #pragma unroll
  for (int r=0;r<4;r++){ u[r]=f2bf(a[r]); u[4+r]=f2bf(b[r]); }
  *(u16x8*)(d + (size_t)i*8) = u;
}

// ================= shared GEMM fragment macros (round-16) =================
#define GEMM_COMMON_DECLS \
  extern __shared__ __attribute__((aligned(16))) char ldsb[]; \
  const int tid  = threadIdx.x; \
  const int lane = tid & 63, wid = tid >> 6; \
  const int g = lane >> 4, l15 = lane & 15; \
  const int wm = wid >> 2, wn = wid & 3; \
  const int nwg = gridDim.x, bid = blockIdx.x; \
  const int swz = (bid & 7) * (nwg >> 3) + (bid >> 3); \
  const int mt = swz >> 3, nt = swz & 7; \
  const int m0 = mt*256, n0 = nt*256; \
  const int srow_l = tid >> 3, slot = tid & 7;

#define RD_A(buf, qa) do{ \
    _Pragma("unroll") for (int i_=0;i_<4;i_++){ \
      int hr = (qa)*64 + i_*16 + l15; \
      const char* p_ = ldsb + (buf)*65536 + wm*16384 + hr*128; \
      _Pragma("unroll") for (int ks_=0;ks_<2;ks_++) \
        av[i_][ks_] = *(const s16x8*)(p_ + (((ks_*4+g) ^ (hr&7))*16)); } }while(0)

#define RD_B(buf, dst, qb) do{ \
    _Pragma("unroll") for (int j_=0;j_<2;j_++){ \
      int hc = (wn&1)*64 + (qb)*32 + j_*16 + l15; \
      const char* p_ = ldsb + (buf)*65536 + 32768 + (wn>>1)*16384 + hc*128; \
      _Pragma("unroll") for (int ks_=0;ks_<2;ks_++) \
        dst[j_][ks_] = *(const s16x8*)(p_ + (((ks_*4+g) ^ (hc&7))*16)); } }while(0)

#define MFMA_PH(qa, qb, bv) do{ \
    __builtin_amdgcn_s_setprio(1); \
    _Pragma("unroll") for (int i_=0;i_<4;i_++) \
      _Pragma("unroll") for (int j_=0;j_<2;j_++) \
        _Pragma("unroll") for (int ks_=0;ks_<2;ks_++) \
          acc[(qa)*4+i_][(qb)*2+j_] = __builtin_amdgcn_mfma_f32_16x16x32_bf16( \
              av[i_][ks_], bv[j_][ks_], acc[(qa)*4+i_][(qb)*2+j_], 0,0,0); \
    __builtin_amdgcn_s_setprio(0); }while(0)

// ---------------- gemm256: r16 fine+deep schedule; store-order-fixed epilogue ----------------
// OUTMODE 0: bf16 [b][h][s][hd]; OUTMODE 1: bf16 V^T [b][h][d][s]; OUTMODE 2: fp32 [m][n]
template<int OUTMODE>
__global__ __launch_bounds__(512, 2) void gemm256(
    const unsigned short* __restrict__ A, const unsigned short* __restrict__ Bw,
    const float* __restrict__ bias, void* __restrict__ Out)
{
  GEMM_COMMON_DECLS
  const int scol = ((slot ^ (srow_l & 7)) * 8);
  const unsigned short* gsrc[4];
  gsrc[0] = A  + (size_t)(m0 +       srow_l)*ND + scol;
  gsrc[1] = A  + (size_t)(m0 + 128 + srow_l)*ND + scol;
  gsrc[2] = Bw + (size_t)(n0 +       srow_l)*ND + scol;
  gsrc[3] = Bw + (size_t)(n0 + 128 + srow_l)*ND + scol;

#define STAGE(buf, p, kt) do{ \
    const unsigned short* s_ = gsrc[p] + (kt); \
    char* d_ = ldsb + (buf)*65536 + ((p)>>1)*32768 + ((p)&1)*16384 + tid*16; \
    gload16(s_, d_); gload16(s_ + (size_t)64*ND, d_ + 8192); }while(0)

// wmode: 0 = steady WAIT_VM8 ; 1 = WAIT_VM0 (tile 30) ; -1 = none (tile 31)
#define HALF(d, ktN, wmode) do{ \
    RD_A(d,0); RD_B(d,bva,0); \
    WAIT_LGKM0(); \
    MFMA_PH(0,0,bva); \
    BARRIER(); \
    RD_B(d,bvb,1); \
    WAIT_LGKM0(); \
    MFMA_PH(0,1,bvb); \
    BARRIER(); \
    RD_A(d,1); \
    if ((ktN)>=0){ STAGE(d,2,ktN); STAGE(d,3,ktN); } \
    WAIT_LGKM0(); \
    MFMA_PH(1,0,bva); \
    BARRIER(); \
    if ((ktN)>=0){ STAGE(d,0,ktN); STAGE(d,1,ktN); } \
    MFMA_PH(1,1,bvb); \
    if ((wmode)==0){ WAIT_VM8(); } \
    else if ((wmode)==1){ WAIT_VM0(); } \
    BARRIER(); \
  }while(0)

  f32x4 acc[8][4];
  s16x8 av[4][2], bva[2][2], bvb[2][2];

  // prologue: tile 0 -> dbuf0 (8 loads), tile 1 -> dbuf1 (8 loads)
  STAGE(0,0,0); STAGE(0,1,0); STAGE(0,2,0); STAGE(0,3,0);
  STAGE(1,0,64); STAGE(1,1,64); STAGE(1,2,64); STAGE(1,3,64);
  #pragma unroll
  for (int i=0;i<8;i++)
    #pragma unroll
    for (int j=0;j<4;j++) acc[i][j] = f32x4{0.f,0.f,0.f,0.f};
  WAIT_VM8();    // tile 0 landed; tile 1 in flight
  BARRIER();

  for (int t = 0; t < 15; ++t) {
    HALF(0, (2*t+2)*64, 0);   // tile 2t   ; stage tile 2t+2 -> dbuf0
    HALF(1, (2*t+3)*64, 0);   // tile 2t+1 ; stage tile 2t+3 -> dbuf1
  }
  HALF(0, -1, 1);             // tile 30 ; drain (tile 31 lands)
  HALF(1, -1, -1);            // tile 31

  // ---------------- epilogue ----------------
  if constexpr (OUTMODE == 0) {
    // store-order fix: fix the output row (s) and walk d consecutively so each
    // 128-B line of [b][h][s][hd] is filled by temporally-adjacent stores.
    float bjv[4];
    #pragma unroll
    for (int jx=0;jx<4;jx++)
      bjv[jx] = bias[n0 + wn*64 + ((jx>>1)<<5) + ((jx&1)<<4) + l15];
    unsigned short* O = (unsigned short*)Out;
    #pragma unroll
    for (int i=0;i<8;i++){
      int mb = m0 + wm*128 + ((i>>2)<<6) + ((i&3)<<4) + g*4;
      int bb = mb >> 8, s0 = mb & 255;
      #pragma unroll
      for (int r=0;r<4;r++){
        #pragma unroll
        for (int jx=0;jx<4;jx++){
          int n = n0 + wn*64 + ((jx>>1)<<5) + ((jx&1)<<4) + l15;
          int h = n >> 7, d = n & 127;
          O[(((size_t)bb*NH + h)*NS + s0 + r)*NHD + d] = f2bf(acc[i][jx][r] + bjv[jx]);
        }
      }
    }
  } else {
    #pragma unroll
    for (int jx=0;jx<4;jx++){
      int n = n0 + wn*64 + ((jx>>1)<<5) + ((jx&1)<<4) + l15;
      float bj = bias[n];
      #pragma unroll
      for (int i=0;i<8;i++){
        int mb = m0 + wm*128 + ((i>>2)<<6) + ((i&3)<<4) + g*4;
        if constexpr (OUTMODE == 2){
          float* O = (float*)Out;
          #pragma unroll
          for (int r=0;r<4;r++) O[(size_t)(mb+r)*ND + n] = acc[i][jx][r] + bj;
        } else {
          unsigned short* O = (unsigned short*)Out;
          int bb = mb >> 8, h = n >> 7, d = n & 127, s0 = mb & 255;
          u16x4 u;
          #pragma unroll
          for (int r=0;r<4;r++) u[r] = f2bf(acc[i][jx][r] + bj);
          *(u16x4*)(O + (((size_t)bb*NH + h)*NHD + d)*NS + s0) = u;
        }
      }
    }
  }
#undef STAGE
#undef HALF
}

// ---------------- fused attention v6 (unchanged from round 16) ----------------
__global__ __launch_bounds__(256, 2) void attn_fused6(
  const unsigned short* __restrict__ Qh, const unsigned short* __restrict__ Kh,
  const unsigned short* __restrict__ VT, const int* __restrict__ mask,
  const float* __restrict__ bias_table, unsigned short* __restrict__ AO)
{
  __shared__ unsigned short KV[256*128];   // 64 KB: K tile, then V^T tile
  char* KVb = (char*)KV;
  const int bid = blockIdx.x;
  const int bh = (((bid >> 3) >> 2) << 3) | (bid & 7);
  const int qt = (bid >> 3) & 3;
  const int b = bh >> 4, h = bh & 15;
  const int tid = threadIdx.x, lane = tid & 63, w = tid >> 6;
  const int g = lane >> 4, l15 = lane & 15;
  const int q = qt*64 + w*16 + l15;

  {
    const unsigned short* Ksrc = Kh + (size_t)bh*NS*NHD;
    int r0 = tid >> 4, sl = tid & 15;
    #pragma unroll
    for (int c=0;c<16;c++){
      int row = c*16 + r0;
      gload16(Ksrc + (size_t)row*NHD + ((sl ^ (row&7))*8), KVb + c*4096 + tid*16);
    }
  }
  const unsigned short* Qrow = Qh + ((size_t)bh*NS + q)*NHD;
  s16x8 bq[4];
  #pragma unroll
  for (int kk=0;kk<4;kk++) bq[kk] = *(const s16x8*)(Qrow + kk*32 + g*8);
  const float* brow = bias_table + ((size_t)h*NS + q)*NS;
  const int*   mrow = mask + b*NS;
  f32x4 br[16];
  i32x4 mr[16];
  #pragma unroll
  for (int kb=0;kb<16;kb++){
    br[kb] = *(const f32x4*)(brow + kb*16 + g*4);
    mr[kb] = *(const i32x4*)(mrow + kb*16 + g*4);
  }

  WAIT_VM0();
  BARRIER();   // K valid

  f32x4 c[16];
  __builtin_amdgcn_s_setprio(1);
  #pragma unroll
  for (int kb=0;kb<16;kb++){
    c[kb] = f32x4{0.f,0.f,0.f,0.f};
    int row = kb*16 + l15;
    #pragma unroll
    for (int kk=0;kk<4;kk++){
      s16x8 a = *(const s16x8*)(KVb + row*256 + (((kk*4+g) ^ (row&7))*16));
      c[kb] = __builtin_amdgcn_mfma_f32_16x16x32_bf16(a, bq[kk], c[kb], 0,0,0);
    }
  }
  __builtin_amdgcn_s_setprio(0);

  WAIT_LGKM0();
  BARRIER();      // K dead -> safe to overwrite

  {
    const unsigned short* Vsrc = VT + (size_t)bh*NHD*NS;
    int r0 = tid >> 5, sl = tid & 31;
    #pragma unroll
    for (int c2=0;c2<16;c2++){
      int row = c2*8 + r0;
      gload16(Vsrc + (size_t)row*NS + ((sl ^ (row&7))*8), KVb + c2*4096 + tid*16);
    }
  }

  const float scale = 0.08838834764831845f;
  float mx = -3.0e38f;
  #pragma unroll
  for (int kb=0;kb<16;kb++){
    #pragma unroll
    for (int r=0;r<4;r++){
      float val = (mr[kb][r] != 0) ? (c[kb][r]*scale + br[kb][r]) : -3.0e38f;
      c[kb][r] = val;
      mx = fmaxf(mx, val);
    }
  }
  mx = fmaxf(mx, __shfl_xor(mx, 16));
  mx = fmaxf(mx, __shfl_xor(mx, 32));
  float sum = 0.f;
  #pragma unroll
  for (int kb=0;kb<16;kb++)
    #pragma unroll
    for (int r=0;r<4;r++){
      float pv = __expf(c[kb][r] - mx);
      c[kb][r] = pv; sum += pv;
    }
  sum += __shfl_xor(sum, 16);
  sum += __shfl_xor(sum, 32);
  float inv = 1.f / sum;

  unsigned int pk[16][2];
  #pragma unroll
  for (int kb=0;kb<16;kb++){
    pk[kb][0] = (unsigned int)f2bf(c[kb][0]*inv) | ((unsigned int)f2bf(c[kb][1]*inv) << 16);
    pk[kb][1] = (unsigned int)f2bf(c[kb][2]*inv) | ((unsigned int)f2bf(c[kb][3]*inv) << 16);
  }

  WAIT_VM0();   // V landed
  BARRIER();

  const int s0l = l15 + ((g&1)<<5), s1l = s0l + 16;
  const int sel = g >> 1;
  s16x8 pb[8];
  #pragma unroll
  for (int kk=0;kk<8;kk++){
    unsigned int e0 = (unsigned int)__shfl((int)pk[2*kk][0],   s0l);
    unsigned int e1 = (unsigned int)__shfl((int)pk[2*kk][1],   s0l);
    unsigned int e2 = (unsigned int)__shfl((int)pk[2*kk][0],   s1l);
    unsigned int e3 = (unsigned int)__shfl((int)pk[2*kk][1],   s1l);
    unsigned int o0 = (unsigned int)__shfl((int)pk[2*kk+1][0], s0l);
    unsigned int o1 = (unsigned int)__shfl((int)pk[2*kk+1][1], s0l);
    unsigned int o2 = (unsigned int)__shfl((int)pk[2*kk+1][0], s1l);
    unsigned int o3 = (unsigned int)__shfl((int)pk[2*kk+1][1], s1l);
    union { unsigned int wd[4]; s16x8 v; } u_;
    u_.wd[0] = sel ? o0 : e0; u_.wd[1] = sel ? o1 : e1;
    u_.wd[2] = sel ? o2 : e2; u_.wd[3] = sel ? o3 : e3;
    pb[kk] = u_.v;
  }

  f32x4 oacc[8];
  __builtin_amdgcn_s_setprio(1);
  #pragma unroll
  for (int dt=0;dt<8;dt++){
    oacc[dt] = f32x4{0.f,0.f,0.f,0.f};
    int row = dt*16 + l15;
    #pragma unroll
    for (int kk=0;kk<8;kk++){
      s16x8 a = *(const s16x8*)(KVb + row*512 + (((kk*4+g) ^ (row&7))*16));
      oacc[dt] = __builtin_amdgcn_mfma_f32_16x16x32_bf16(a, pb[kk], oacc[dt], 0,0,0);
    }
  }
  __builtin_amdgcn_s_setprio(0);

  #pragma unroll
  for (int dt=0;dt<8;dt++){
    u16x4 u;
    #pragma unroll
    for (int r=0;r<4;r++) u[r] = f2bf(oacc[dt][r]);
    *(u16x4*)(AO + ((size_t)b*NS + q)*ND + h*NHD + dt*16 + g*4) = u;
  }
}

extern "C" void kernel_launch(void* const* d_in, const int* in_sizes, int n_in,
                              void* d_out, int out_size, void* d_ws, size_t ws_size,
                              hipStream_t stream)
{
  const float* q  = (const float*)d_in[0];
  const float* k  = (const float*)d_in[1];
  const float* v  = (const float*)d_in[2];
  const int* mask = (const int*)d_in[3];
  const float* Wq = (const float*)d_in[4];
  const float* bq = (const float*)d_in[5];
  const float* Wk = (const float*)d_in[6];
  const float* bk = (const float*)d_in[7];
  const float* Wv = (const float*)d_in[8];
  const float* bv = (const float*)d_in[9];
  const float* Wo = (const float*)d_in[10];
  const float* bo = (const float*)d_in[11];
  const float* bias_table = (const float*)d_in[12];

  // workspace layout, max 352 MiB (proven in rounds 1/3):
  //   Wqb [0,8M) Wkb [8M,16M) Wvb [16M,24M) Wob [24M,32M)
  //   tmp [32M,96M) (full-M bf16 activations, reused q->k->v)
  //   Qh [96M,160M)  Kh [160M,224M)  VT [224M,288M)  AO [288M,352M)
  char* ws = (char*)d_ws;
  unsigned short* Wqb = (unsigned short*)(ws + 0);
  unsigned short* Wkb = (unsigned short*)(ws + 8388608);
  unsigned short* Wvb = (unsigned short*)(ws + 16777216);
  unsigned short* Wob = (unsigned short*)(ws + 25165824);
  unsigned short* tmp = (unsigned short*)(ws + 33554432);
  unsigned short* Qh  = (unsigned short*)(ws + 100663296);
  unsigned short* Kh  = (unsigned short*)(ws + 167772160);
  unsigned short* VT  = (unsigned short*)(ws + 234881024);
  unsigned short* AO  = (unsigned short*)(ws + 301989888);

  hipFuncSetAttribute((const void*)gemm256<0>, hipFuncAttributeMaxDynamicSharedMemorySize, 131072);
  hipFuncSetAttribute((const void*)gemm256<1>, hipFuncAttributeMaxDynamicSharedMemorySize, 131072);
  hipFuncSetAttribute((const void*)gemm256<2>, hipFuncAttributeMaxDynamicSharedMemorySize, 131072);

  wconv4<<<8192,256,0,stream>>>(Wq,Wk,Wv,Wo, Wqb,Wkb,Wvb,Wob);

  const float* acts[3] = {q, k, v};
  const unsigned short* wgt[3] = {Wqb, Wkb, Wvb};
  const float* bia[3] = {bq, bk, bv};
  unsigned short* outs[3] = {Qh, Kh, VT};

  for (int x = 0; x < 3; ++x) {
    wconv<<<16384,256,0,stream>>>(acts[x], tmp, 4194304);
    if (x < 2)
      gemm256<0><<<512,512,131072,stream>>>(tmp, wgt[x], bia[x], outs[x]);
    else
      gemm256<1><<<512,512,131072,stream>>>(tmp, wgt[x], bia[x], outs[x]);
  }

  attn_fused6<<<4096,256,0,stream>>>(Qh,Kh,VT,mask,bias_table,AO);
  gemm256<2><<<512,512,131072,stream>>>(AO,Wob,bo,(float*)d_out);
}

// Round 19
// 702.471 us; speedup vs baseline: 1.0312x; 1.0001x over previous
//
#include <hip/hip_runtime.h>
#include <hip/hip_bf16.h>

typedef __attribute__((ext_vector_type(4))) float f32x4;
typedef __attribute__((ext_vector_type(8))) short s16x8;
typedef __attribute__((ext_vector_type(4))) unsigned short u16x4;
typedef __attribute__((ext_vector_type(8))) unsigned short u16x8;
typedef __attribute__((ext_vector_type(4))) int i32x4;

#define NB 64
#define NS 256
#define ND 2048
#define NH 16
#define NHD 128

__device__ __forceinline__ unsigned short f2bf(float f){
  unsigned int u = __float_as_uint(f);
  u += 0x7fffu + ((u >> 16) & 1u);
  return (unsigned short)(u >> 16);
}

__device__ __forceinline__ void gload16(const void* g, void* l){
  __builtin_amdgcn_global_load_lds(
    (const __attribute__((address_space(1))) unsigned int*)g,
    (__attribute__((address_space(3))) unsigned int*)l, 16, 0, 0);
}

#define SBAR()  __builtin_amdgcn_sched_barrier(0)
#define BARRIER() do{ SBAR(); __builtin_amdgcn_s_barrier(); SBAR(); }while(0)
#define WAIT_LGKM0() do{ asm volatile("s_waitcnt lgkmcnt(0)" ::: "memory"); SBAR(); }while(0)
#define WAIT_VM0()   do{ asm volatile("s_waitcnt vmcnt(0)"   ::: "memory"); SBAR(); }while(0)
#define WAIT_VM8()   do{ asm volatile("s_waitcnt vmcnt(8)"   ::: "memory"); SBAR(); }while(0)

// ---------------- fp32 -> bf16 conversion ----------------
__global__ __launch_bounds__(256) void wconv(const float* __restrict__ s,
                                             unsigned short* __restrict__ d, int n8){
  int i = blockIdx.x*256 + threadIdx.x;
  if (i >= n8) return;
  f32x4 a = *(const f32x4*)(s + (size_t)i*8);
  f32x4 b = *(const f32x4*)(s + (size_t)i*8 + 4);
  u16x8 u;
  #pragma unroll
  for (int r=0;r<4;r++){ u[r]=f2bf(a[r]); u[4+r]=f2bf(b[r]); }
  *(u16x8*)(d + (size_t)i*8) = u;
}

// all four weight matrices in one dispatch (grid 8192, 2048 blocks each)
__global__ __launch_bounds__(256) void wconv4(
  const float* __restrict__ s0, const float* __restrict__ s1,
  const float* __restrict__ s2, const float* __restrict__ s3,
  unsigned short* __restrict__ d0, unsigned short* __restrict__ d1,
  unsigned short* __restrict__ d2, unsigned short* __restrict__ d3)
{
  int j = blockIdx.x >> 11;
  const float* s = (j==0)?s0:(j==1)?s1:(j==2)?s2:s3;
  unsigned short* d = (j==0)?d0:(j==1)?d1:(j==2)?d2:d3;
  int i = (blockIdx.x & 2047)*256 + threadIdx.x;
  f32x4 a = *(const f32x4*)(s + (size_t)i*8);
  f32x4 b = *(const f32x4*)(s + (size_t)i*8 + 4);
  u16x8 u;
  #pragma unroll
  for (int r=0;r<4;r++){ u[r]=f2bf(a[r]); u[4+r]=f2bf(b[r]); }
  *(u16x8*)(d + (size_t)i*8) = u;
}

// ================= shared GEMM fragment macros (round-16) =================
#define GEMM_COMMON_DECLS \
  extern __shared__ __attribute__((aligned(16))) char ldsb[]; \
  const int tid  = threadIdx.x; \
  const int lane = tid & 63, wid = tid >> 6; \
  const int g = lane >> 4, l15 = lane & 15; \
  const int wm = wid >> 2, wn = wid & 3; \
  const int nwg = gridDim.x, bid = blockIdx.x; \
  const int swz = (bid & 7) * (nwg >> 3) + (bid >> 3); \
  const int mt = swz >> 3, nt = swz & 7; \
  const int m0 = mt*256, n0 = nt*256; \
  const int srow_l = tid >> 3, slot = tid & 7;

#define RD_A(buf, qa) do{ \
    _Pragma("unroll") for (int i_=0;i_<4;i_++){ \
      int hr = (qa)*64 + i_*16 + l15; \
      const char* p_ = ldsb + (buf)*65536 + wm*16384 + hr*128; \
      _Pragma("unroll") for (int ks_=0;ks_<2;ks_++) \
        av[i_][ks_] = *(const s16x8*)(p_ + (((ks_*4+g) ^ (hr&7))*16)); } }while(0)

#define RD_B(buf, dst, qb) do{ \
    _Pragma("unroll") for (int j_=0;j_<2;j_++){ \
      int hc = (wn&1)*64 + (qb)*32 + j_*16 + l15; \
      const char* p_ = ldsb + (buf)*65536 + 32768 + (wn>>1)*16384 + hc*128; \
      _Pragma("unroll") for (int ks_=0;ks_<2;ks_++) \
        dst[j_][ks_] = *(const s16x8*)(p_ + (((ks_*4+g) ^ (hc&7))*16)); } }while(0)

#define MFMA_PH(qa, qb, bv) do{ \
    __builtin_amdgcn_s_setprio(1); \
    _Pragma("unroll") for (int i_=0;i_<4;i_++) \
      _Pragma("unroll") for (int j_=0;j_<2;j_++) \
        _Pragma("unroll") for (int ks_=0;ks_<2;ks_++) \
          acc[(qa)*4+i_][(qb)*2+j_] = __builtin_amdgcn_mfma_f32_16x16x32_bf16( \
              av[i_][ks_], bv[j_][ks_], acc[(qa)*4+i_][(qb)*2+j_], 0,0,0); \
    __builtin_amdgcn_s_setprio(0); }while(0)

// ---------------- gemm256: r18 base; in-loop lgkm waits now COMPILER-MANAGED ----------------
// Safety of removing explicit lgkmcnt(0): RD_* are compiler-visible LDS loads,
// so each wave's reads complete before its dependent MFMA issues (compiler
// inserts minimal counted lgkmcnt), which precedes the wave's phase-end
// s_barrier. Dead-region staging proofs therefore hold unchanged:
//   STAGE d.B0/B1 at P3/P4: B last read P1(bva)/P2(bvb); those reads landed
//     before MFMA(0,0)/(0,1) issued, before the P1/P2-end barriers.
//   STAGE d.A0/A1 at P4: A last read P3 (RD_A(d,1)); landed before MFMA(1,0),
//     before P3-end barrier.
// Boundary WAIT_VM8 unchanged (retires tile T+1's 8 loads, T+2's in flight).
// OUTMODE 0: bf16 [b][h][s][hd]; OUTMODE 1: bf16 V^T [b][h][d][s]; OUTMODE 2: fp32 [m][n]
template<int OUTMODE>
__global__ __launch_bounds__(512, 2) void gemm256(
    const unsigned short* __restrict__ A, const unsigned short* __restrict__ Bw,
    const float* __restrict__ bias, void* __restrict__ Out)
{
  GEMM_COMMON_DECLS
  const int scol = ((slot ^ (srow_l & 7)) * 8);
  const unsigned short* gsrc[4];
  gsrc[0] = A  + (size_t)(m0 +       srow_l)*ND + scol;
  gsrc[1] = A  + (size_t)(m0 + 128 + srow_l)*ND + scol;
  gsrc[2] = Bw + (size_t)(n0 +       srow_l)*ND + scol;
  gsrc[3] = Bw + (size_t)(n0 + 128 + srow_l)*ND + scol;

#define STAGE(buf, p, kt) do{ \
    const unsigned short* s_ = gsrc[p] + (kt); \
    char* d_ = ldsb + (buf)*65536 + ((p)>>1)*32768 + ((p)&1)*16384 + tid*16; \
    gload16(s_, d_); gload16(s_ + (size_t)64*ND, d_ + 8192); }while(0)

// wmode: 0 = steady WAIT_VM8 ; 1 = WAIT_VM0 (tile 30) ; -1 = none (tile 31)
#define HALF(d, ktN, wmode) do{ \
    RD_A(d,0); RD_B(d,bva,0); \
    MFMA_PH(0,0,bva); \
    BARRIER(); \
    RD_B(d,bvb,1); \
    MFMA_PH(0,1,bvb); \
    BARRIER(); \
    RD_A(d,1); \
    if ((ktN)>=0){ STAGE(d,2,ktN); STAGE(d,3,ktN); } \
    MFMA_PH(1,0,bva); \
    BARRIER(); \
    if ((ktN)>=0){ STAGE(d,0,ktN); STAGE(d,1,ktN); } \
    MFMA_PH(1,1,bvb); \
    if ((wmode)==0){ WAIT_VM8(); } \
    else if ((wmode)==1){ WAIT_VM0(); } \
    BARRIER(); \
  }while(0)

  f32x4 acc[8][4];
  s16x8 av[4][2], bva[2][2], bvb[2][2];

  // prologue: tile 0 -> dbuf0 (8 loads), tile 1 -> dbuf1 (8 loads)
  STAGE(0,0,0); STAGE(0,1,0); STAGE(0,2,0); STAGE(0,3,0);
  STAGE(1,0,64); STAGE(1,1,64); STAGE(1,2,64); STAGE(1,3,64);
  #pragma unroll
  for (int i=0;i<8;i++)
    #pragma unroll
    for (int j=0;j<4;j++) acc[i][j] = f32x4{0.f,0.f,0.f,0.f};
  WAIT_VM8();    // tile 0 landed; tile 1 in flight
  BARRIER();

  for (int t = 0; t < 15; ++t) {
    HALF(0, (2*t+2)*64, 0);   // tile 2t   ; stage tile 2t+2 -> dbuf0
    HALF(1, (2*t+3)*64, 0);   // tile 2t+1 ; stage tile 2t+3 -> dbuf1
  }
  HALF(0, -1, 1);             // tile 30 ; drain (tile 31 lands)
  HALF(1, -1, -1);            // tile 31

  // ---------------- epilogue (round-18 store-order-fixed) ----------------
  if constexpr (OUTMODE == 0) {
    float bjv[4];
    #pragma unroll
    for (int jx=0;jx<4;jx++)
      bjv[jx] = bias[n0 + wn*64 + ((jx>>1)<<5) + ((jx&1)<<4) + l15];
    unsigned short* O = (unsigned short*)Out;
    #pragma unroll
    for (int i=0;i<8;i++){
      int mb = m0 + wm*128 + ((i>>2)<<6) + ((i&3)<<4) + g*4;
      int bb = mb >> 8, s0 = mb & 255;
      #pragma unroll
      for (int r=0;r<4;r++){
        #pragma unroll
        for (int jx=0;jx<4;jx++){
          int n = n0 + wn*64 + ((jx>>1)<<5) + ((jx&1)<<4) + l15;
          int h = n >> 7, d = n & 127;
          O[(((size_t)bb*NH + h)*NS + s0 + r)*NHD + d] = f2bf(acc[i][jx][r] + bjv[jx]);
        }
      }
    }
  } else {
    #pragma unroll
    for (int jx=0;jx<4;jx++){
      int n = n0 + wn*64 + ((jx>>1)<<5) + ((jx&1)<<4) + l15;
      float bj = bias[n];
      #pragma unroll
      for (int i=0;i<8;i++){
        int mb = m0 + wm*128 + ((i>>2)<<6) + ((i&3)<<4) + g*4;
        if constexpr (OUTMODE == 2){
          float* O = (float*)Out;
          #pragma unroll
          for (int r=0;r<4;r++) O[(size_t)(mb+r)*ND + n] = acc[i][jx][r] + bj;
        } else {
          unsigned short* O = (unsigned short*)Out;
          int bb = mb >> 8, h = n >> 7, d = n & 127, s0 = mb & 255;
          u16x4 u;
          #pragma unroll
          for (int r=0;r<4;r++) u[r] = f2bf(acc[i][jx][r] + bj);
          *(u16x4*)(O + (((size_t)bb*NH + h)*NHD + d)*NS + s0) = u;
        }
      }
    }
  }
#undef STAGE
#undef HALF
}

// ---------------- fused attention v6 (unchanged from round 16) ----------------
__global__ __launch_bounds__(256, 2) void attn_fused6(
  const unsigned short* __restrict__ Qh, const unsigned short* __restrict__ Kh,
  const unsigned short* __restrict__ VT, const int* __restrict__ mask,
  const float* __restrict__ bias_table, unsigned short* __restrict__ AO)
{
  __shared__ unsigned short KV[256*128];   // 64 KB: K tile, then V^T tile
  char* KVb = (char*)KV;
  const int bid = blockIdx.x;
  const int bh = (((bid >> 3) >> 2) << 3) | (bid & 7);
  const int qt = (bid >> 3) & 3;
  const int b = bh >> 4, h = bh & 15;
  const int tid = threadIdx.x, lane = tid & 63, w = tid >> 6;
  const int g = lane >> 4, l15 = lane & 15;
  const int q = qt*64 + w*16 + l15;

  {
    const unsigned short* Ksrc = Kh + (size_t)bh*NS*NHD;
    int r0 = tid >> 4, sl = tid & 15;
    #pragma unroll
    for (int c=0;c<16;c++){
      int row = c*16 + r0;
      gload16(Ksrc + (size_t)row*NHD + ((sl ^ (row&7))*8), KVb + c*4096 + tid*16);
    }
  }
  const unsigned short* Qrow = Qh + ((size_t)bh*NS + q)*NHD;
  s16x8 bq[4];
  #pragma unroll
  for (int kk=0;kk<4;kk++) bq[kk] = *(const s16x8*)(Qrow + kk*32 + g*8);
  const float* brow = bias_table + ((size_t)h*NS + q)*NS;
  const int*   mrow = mask + b*NS;
  f32x4 br[16];
  i32x4 mr[16];
  #pragma unroll
  for (int kb=0;kb<16;kb++){
    br[kb] = *(const f32x4*)(brow + kb*16 + g*4);
    mr[kb] = *(const i32x4*)(mrow + kb*16 + g*4);
  }

  WAIT_VM0();
  BARRIER();   // K valid

  f32x4 c[16];
  __builtin_amdgcn_s_setprio(1);
  #pragma unroll
  for (int kb=0;kb<16;kb++){
    c[kb] = f32x4{0.f,0.f,0.f,0.f};
    int row = kb*16 + l15;
    #pragma unroll
    for (int kk=0;kk<4;kk++){
      s16x8 a = *(const s16x8*)(KVb + row*256 + (((kk*4+g) ^ (row&7))*16));
      c[kb] = __builtin_amdgcn_mfma_f32_16x16x32_bf16(a, bq[kk], c[kb], 0,0,0);
    }
  }
  __builtin_amdgcn_s_setprio(0);

  WAIT_LGKM0();
  BARRIER();      // K dead -> safe to overwrite

  {
    const unsigned short* Vsrc = VT + (size_t)bh*NHD*NS;
    int r0 = tid >> 5, sl = tid & 31;
    #pragma unroll
    for (int c2=0;c2<16;c2++){
      int row = c2*8 + r0;
      gload16(Vsrc + (size_t)row*NS + ((sl ^ (row&7))*8), KVb + c2*4096 + tid*16);
    }
  }

  const float scale = 0.08838834764831845f;
  float mx = -3.0e38f;
  #pragma unroll
  for (int kb=0;kb<16;kb++){
    #pragma unroll
    for (int r=0;r<4;r++){
      float val = (mr[kb][r] != 0) ? (c[kb][r]*scale + br[kb][r]) : -3.0e38f;
      c[kb][r] = val;
      mx = fmaxf(mx, val);
    }
  }
  mx = fmaxf(mx, __shfl_xor(mx, 16));
  mx = fmaxf(mx, __shfl_xor(mx, 32));
  float sum = 0.f;
  #pragma unroll
  for (int kb=0;kb<16;kb++)
    #pragma unroll
    for (int r=0;r<4;r++){
      float pv = __expf(c[kb][r] - mx);
      c[kb][r] = pv; sum += pv;
    }
  sum += __shfl_xor(sum, 16);
  sum += __shfl_xor(sum, 32);
  float inv = 1.f / sum;

  unsigned int pk[16][2];
  #pragma unroll
  for (int kb=0;kb<16;kb++){
    pk[kb][0] = (unsigned int)f2bf(c[kb][0]*inv) | ((unsigned int)f2bf(c[kb][1]*inv) << 16);
    pk[kb][1] = (unsigned int)f2bf(c[kb][2]*inv) | ((unsigned int)f2bf(c[kb][3]*inv) << 16);
  }

  WAIT_VM0();   // V landed
  BARRIER();

  const int s0l = l15 + ((g&1)<<5), s1l = s0l + 16;
  const int sel = g >> 1;
  s16x8 pb[8];
  #pragma unroll
  for (int kk=0;kk<8;kk++){
    unsigned int e0 = (unsigned int)__shfl((int)pk[2*kk][0],   s0l);
    unsigned int e1 = (unsigned int)__shfl((int)pk[2*kk][1],   s0l);
    unsigned int e2 = (unsigned int)__shfl((int)pk[2*kk][0],   s1l);
    unsigned int e3 = (unsigned int)__shfl((int)pk[2*kk][1],   s1l);
    unsigned int o0 = (unsigned int)__shfl((int)pk[2*kk+1][0], s0l);
    unsigned int o1 = (unsigned int)__shfl((int)pk[2*kk+1][1], s0l);
    unsigned int o2 = (unsigned int)__shfl((int)pk[2*kk+1][0], s1l);
    unsigned int o3 = (unsigned int)__shfl((int)pk[2*kk+1][1], s1l);
    union { unsigned int wd[4]; s16x8 v; } u_;
    u_.wd[0] = sel ? o0 : e0; u_.wd[1] = sel ? o1 : e1;
    u_.wd[2] = sel ? o2 : e2; u_.wd[3] = sel ? o3 : e3;
    pb[kk] = u_.v;
  }

  f32x4 oacc[8];
  __builtin_amdgcn_s_setprio(1);
  #pragma unroll
  for (int dt=0;dt<8;dt++){
    oacc[dt] = f32x4{0.f,0.f,0.f,0.f};
    int row = dt*16 + l15;
    #pragma unroll
    for (int kk=0;kk<8;kk++){
      s16x8 a = *(const s16x8*)(KVb + row*512 + (((kk*4+g) ^ (row&7))*16));
      oacc[dt] = __builtin_amdgcn_mfma_f32_16x16x32_bf16(a, pb[kk], oacc[dt], 0,0,0);
    }
  }
  __builtin_amdgcn_s_setprio(0);

  #pragma unroll
  for (int dt=0;dt<8;dt++){
    u16x4 u;
    #pragma unroll
    for (int r=0;r<4;r++) u[r] = f2bf(oacc[dt][r]);
    *(u16x4*)(AO + ((size_t)b*NS + q)*ND + h*NHD + dt*16 + g*4) = u;
  }
}

extern "C" void kernel_launch(void* const* d_in, const int* in_sizes, int n_in,
                              void* d_out, int out_size, void* d_ws, size_t ws_size,
                              hipStream_t stream)
{
  const float* q  = (const float*)d_in[0];
  const float* k  = (const float*)d_in[1];
  const float* v  = (const float*)d_in[2];
  const int* mask = (const int*)d_in[3];
  const float* Wq = (const float*)d_in[4];
  const float* bq = (const float*)d_in[5];
  const float* Wk = (const float*)d_in[6];
  const float* bk = (const float*)d_in[7];
  const float* Wv = (const float*)d_in[8];
  const float* bv = (const float*)d_in[9];
  const float* Wo = (const float*)d_in[10];
  const float* bo = (const float*)d_in[11];
  const float* bias_table = (const float*)d_in[12];

  // workspace layout, max 352 MiB (proven in rounds 1/3):
  //   Wqb [0,8M) Wkb [8M,16M) Wvb [16M,24M) Wob [24M,32M)
  //   tmp [32M,96M) (full-M bf16 activations, reused q->k->v)
  //   Qh [96M,160M)  Kh [160M,224M)  VT [224M,288M)  AO [288M,352M)
  char* ws = (char*)d_ws;
  unsigned short* Wqb = (unsigned short*)(ws + 0);
  unsigned short* Wkb = (unsigned short*)(ws + 8388608);
  unsigned short* Wvb = (unsigned short*)(ws + 16777216);
  unsigned short* Wob = (unsigned short*)(ws + 25165824);
  unsigned short* tmp = (unsigned short*)(ws + 33554432);
  unsigned short* Qh  = (unsigned short*)(ws + 100663296);
  unsigned short* Kh  = (unsigned short*)(ws + 167772160);
  unsigned short* VT  = (unsigned short*)(ws + 234881024);
  unsigned short* AO  = (unsigned short*)(ws + 301989888);

  hipFuncSetAttribute((const void*)gemm256<0>, hipFuncAttributeMaxDynamicSharedMemorySize, 131072);
  hipFuncSetAttribute((const void*)gemm256<1>, hipFuncAttributeMaxDynamicSharedMemorySize, 131072);
  hipFuncSetAttribute((const void*)gemm256<2>, hipFuncAttributeMaxDynamicSharedMemorySize, 131072);

  wconv4<<<8192,256,0,stream>>>(Wq,Wk,Wv,Wo, Wqb,Wkb,Wvb,Wob);

  const float* acts[3] = {q, k, v};
  const unsigned short* wgt[3] = {Wqb, Wkb, Wvb};
  const float* bia[3] = {bq, bk, bv};
  unsigned short* outs[3] = {Qh, Kh, VT};

  for (int x = 0; x < 3; ++x) {
    wconv<<<16384,256,0,stream>>>(acts[x], tmp, 4194304);
    if (x < 2)
      gemm256<0><<<512,512,131072,stream>>>(tmp, wgt[x], bia[x], outs[x]);
    else
      gemm256<1><<<512,512,131072,stream>>>(tmp, wgt[x], bia[x], outs[x]);
  }

  attn_fused6<<<4096,256,0,stream>>>(Qh,Kh,VT,mask,bias_table,AO);
  gemm256<2><<<512,512,131072,stream>>>(AO,Wob,bo,(float*)d_out);
}